// Round 7
// baseline (205.317 us; speedup 1.0000x reference)
//
#include <hip/hip_runtime.h>

// PositionalWordEmbedding: out[b,s,d] = W[x[b,s]][d] + pe[s][d]
//   pe[s,d] = sin(s * 10000^(-d/256))      d even
//           = cos(s * 10000^(-(d-1)/256))  d odd
//
// B=32, S=4096, D=256, VOCAB=50257. Output fp32, 128 MiB -> memory-bound.
//
// One thread owns one (s, d4) where d4 indexes a float4 (4 consecutive d).
// It computes the 2 needed (sin,cos) pairs ONCE, then loops over the 32
// batches: gather W row segment (float4, coalesced across the wave since
// 64 lanes = 64 float4 = one full 1KiB row), add, store.

#define SEQ   4096
#define DIM   256
#define BATCH 32
#define D4    (DIM / 4)   // 64 float4 per row

__global__ __launch_bounds__(256)
void pwe_kernel(const int* __restrict__ x,
                const float4* __restrict__ W4,
                float4* __restrict__ out4) {
    int tid = blockIdx.x * blockDim.x + threadIdx.x;   // 0 .. SEQ*D4-1
    if (tid >= SEQ * D4) return;
    int s  = tid >> 6;        // sequence position (same for all 64 lanes of a wave)
    int d4 = tid & 63;        // which float4 within the row
    int d0 = d4 * 4;          // even; four dims: d0(e), d0+1(o), d0+2(e), d0+3(o)

    // pe for this thread's 4 dims (precise math: args up to ~4095 rad)
    float f0 = powf(10000.0f, -(float)d0       / (float)DIM);
    float f2 = powf(10000.0f, -(float)(d0 + 2) / (float)DIM);
    float p  = (float)s;
    float s0, c0, s2, c2;
    sincosf(p * f0, &s0, &c0);
    sincosf(p * f2, &s2, &c2);
    float4 pe;
    pe.x = s0; pe.y = c0; pe.z = s2; pe.w = c2;

    #pragma unroll 8
    for (int b = 0; b < BATCH; ++b) {
        int token = x[b * SEQ + s];                       // wave-uniform broadcast
        float4 w = W4[(size_t)token * D4 + d4];           // coalesced row gather
        float4 o;
        o.x = w.x + pe.x;
        o.y = w.y + pe.y;
        o.z = w.z + pe.z;
        o.w = w.w + pe.w;
        out4[((size_t)b * SEQ + s) * D4 + d4] = o;        // coalesced store
    }
}

extern "C" void kernel_launch(void* const* d_in, const int* in_sizes, int n_in,
                              void* d_out, int out_size, void* d_ws, size_t ws_size,
                              hipStream_t stream) {
    const int*   x = (const int*)d_in[0];      // [32, 4096] token ids
    const float* W = (const float*)d_in[1];    // [50257, 256] fp32
    float*     out = (float*)d_out;            // [32, 4096, 256] fp32

    const int total = SEQ * D4;                // 262144 threads
    const int block = 256;
    const int grid  = (total + block - 1) / block;  // 1024 blocks
    pwe_kernel<<<grid, block, 0, stream>>>(x, (const float4*)W, (float4*)out);
}

// Round 9
// 184.184 us; speedup vs baseline: 1.1147x; 1.1147x over previous
//
#include <hip/hip_runtime.h>

// PositionalWordEmbedding: out[b,s,d] = W[x[b,s]][d] + pe[s][d]
// B=32, S=4096, D=256, VOCAB=50257. Output fp32, 128 MiB -> memory-bound.
//
// R7 post-mortem: 79 us/dispatch at only 22-33% HBM peak, Occupancy 33%,
// VALUBusy 7% -> latency-bound, not BW-bound (fillBuffer hits 84% on same
// chip). Cause: 1024 blocks = 4 blocks/CU, each thread serially doing 32
// dependent gather iterations.
//
// Fix: batches-per-thread 32 -> 4, grid 1024 -> 8192 blocks (32 blocks/CU
// queue; low VGPR permits 8 waves/SIMD so near-100% occupancy). Trig is
// recomputed 8x (2 sincos/thread) but hides under memory latency.
// Token loads issued up-front; nontemporal stores keep the 136 MB out
// stream from thrashing W's cache lines.
//
// R8: __builtin_nontemporal_store needs a native vector type, not HIP's
// float4 class -> use ext_vector_type(4) float.

#define SEQ   4096
#define DIM   256
#define BATCH 32
#define D4    (DIM / 4)      // 64 float4 per row
#define BPT   4              // batches per thread
#define NGRP  (BATCH / BPT)  // 8 batch-groups
#define SD    (SEQ * D4)     // 262144 = 2^18 (s,d4) slots

typedef float f32x4 __attribute__((ext_vector_type(4)));

__global__ __launch_bounds__(256)
void pwe_kernel(const int* __restrict__ x,
                const f32x4* __restrict__ W4,
                f32x4* __restrict__ out4) {
    int tid = blockIdx.x * blockDim.x + threadIdx.x;   // 0 .. SD*NGRP-1
    int sd  = tid & (SD - 1);     // (s,d4), wave-aligned: lanes share s
    int bg  = tid >> 18;          // batch group 0..7
    int s   = sd >> 6;            // sequence position (uniform per wave)
    int d4  = sd & 63;            // float4 index within row
    int d0  = d4 * 4;             // dims d0(e), d0+1(o), d0+2(e), d0+3(o)

    // pe for this thread's 4 dims (precise math: args up to ~4095 rad)
    float f0 = powf(10000.0f, -(float)d0       / (float)DIM);
    float f2 = powf(10000.0f, -(float)(d0 + 2) / (float)DIM);
    float p  = (float)s;
    float s0, c0, s2, c2;
    sincosf(p * f0, &s0, &c0);
    sincosf(p * f2, &s2, &c2);
    f32x4 pe;
    pe.x = s0; pe.y = c0; pe.z = s2; pe.w = c2;

    const int b0 = bg * BPT;

    // issue all token loads first (independent, wave-uniform broadcasts)
    int tok[BPT];
    #pragma unroll
    for (int i = 0; i < BPT; ++i)
        tok[i] = x[(b0 + i) * SEQ + s];

    #pragma unroll
    for (int i = 0; i < BPT; ++i) {
        f32x4 w = W4[(size_t)tok[i] * D4 + d4];           // coalesced row gather
        f32x4 o = w + pe;
        __builtin_nontemporal_store(
            o, &out4[((size_t)(b0 + i) * SEQ + s) * D4 + d4]);  // coalesced
    }
}

extern "C" void kernel_launch(void* const* d_in, const int* in_sizes, int n_in,
                              void* d_out, int out_size, void* d_ws, size_t ws_size,
                              hipStream_t stream) {
    const int*   x = (const int*)d_in[0];      // [32, 4096] token ids
    const float* W = (const float*)d_in[1];    // [50257, 256] fp32
    float*     out = (float*)d_out;            // [32, 4096, 256] fp32

    const int total = SD * NGRP;               // 2,097,152 threads
    const int block = 256;
    const int grid  = total / block;           // 8192 blocks
    pwe_kernel<<<grid, block, 0, stream>>>(x, (const f32x4*)W, (f32x4*)out);
}